// Round 3
// baseline (1111.479 us; speedup 1.0000x reference)
//
#include <hip/hip_runtime.h>

// Mesh2: out3 = [out1||out2] @ W_comb^T + b_comb ; out4 = mean(self+3nbrs) @ W_agg^T + b_agg
// R2: passed at 600us but latency-bound (31% HBM, MfmaUtil 11%, VGPR=56 -> no MLP).
// R3: T14 async-STAGE pipeline: 3 tiles/block, reg-stage tile t+1 during compute of t,
//     raw s_barrier (no vmcnt drain) + explicit lgkmcnt(0). nbr idx preloaded 2 tiles ahead.

typedef __bf16 bf16x8 __attribute__((ext_vector_type(8)));
typedef float f32x4 __attribute__((ext_vector_type(4)));

#define N_NODES 200000
#define BM 32
#define NTILES (N_NODES / BM)  // 6250
#define TPB 3                  // tiles per block
#define ROWC 520               // 512 + 8 pad (bf16) -> 2-way-bank ds_read_b128 (free, m136)
#define ROWA 264               // 256 + 8 pad

__device__ __forceinline__ unsigned short f2bf(float x) {
  union { float f; unsigned int u; } v; v.f = x;
  return (unsigned short)((v.u + 0x7FFFu + ((v.u >> 16) & 1u)) >> 16);  // RNE
}

__device__ __forceinline__ void st_bf4(unsigned short* p, float4 f) {
  uint2 w;
  w.x = (unsigned int)f2bf(f.x) | ((unsigned int)f2bf(f.y) << 16);
  w.y = (unsigned int)f2bf(f.z) | ((unsigned int)f2bf(f.w) << 16);
  *reinterpret_cast<uint2*>(p) = w;
}

// Pack W (f32, row-major [O][K]) -> bf16 MFMA-B-fragment-linear layout:
// tile (nt,kt): lane l holds W[nt*16 + (l&15)][kt*32 + (l>>4)*8 + j], j=0..7,
// at P[tile*512 + l*8 + j].
__global__ void pack_w_kernel(const float* __restrict__ Wc,
                              const float* __restrict__ Wa,
                              unsigned short* __restrict__ Pc,
                              unsigned short* __restrict__ Pa) {
  int t = blockIdx.x * 256 + threadIdx.x;
  if (t >= (512 + 256) * 64) return;
  int lane = t & 63;
  int tile = t >> 6;
  const float* W;
  unsigned short* P;
  int K, kt_n;
  if (tile < 512) { W = Wc; P = Pc; K = 512; kt_n = 16; }
  else { tile -= 512; W = Wa; P = Pa; K = 256; kt_n = 8; }
  int nt = tile / kt_n;
  int kt = tile - nt * kt_n;
  int row = nt * 16 + (lane & 15);
  int k0 = kt * 32 + (lane >> 4) * 8;
  const float* src = W + (size_t)row * K + k0;
  unsigned short* dst = P + (size_t)tile * 512 + lane * 8;
#pragma unroll
  for (int j = 0; j < 8; ++j) dst[j] = f2bf(src[j]);
}

__global__ __launch_bounds__(512) void mesh_fused_kernel(
    const float* __restrict__ out1,
    const float* __restrict__ out2,
    const int* __restrict__ nbr,
    const unsigned short* __restrict__ Pc,
    const unsigned short* __restrict__ Pa,
    const float* __restrict__ b_comb,
    const float* __restrict__ b_agg,
    float* __restrict__ outp) {
  __shared__ unsigned short Acomb[BM * ROWC];
  __shared__ unsigned short Aagg[BM * ROWA];

  const int tid = threadIdx.x;
  const int ln = tid >> 4;   // local node 0..31 (stage role)
  const int c16 = tid & 15;  // chunk lane (stage role)
  const int wave = tid >> 6, lane = tid & 63;
  const int l15 = lane & 15, l4 = lane >> 4;

  const int t0 = blockIdx.x * TPB;
  const int tEnd = (t0 + TPB < NTILES) ? t0 + TPB : NTILES;

  // bias: cols fixed per thread for the whole block -> hoist
  float bcv[4], bav[4];
#pragma unroll
  for (int n = 0; n < 4; ++n) {
    const int col = wave * 64 + n * 16 + l15;
    bcv[n] = b_comb[col];
    bav[n] = b_agg[col];
  }

  // staged registers for one tile (20 x float4 = 80 VGPR, deliberate)
  float4 s1[4], s2[4], g0v[4], g1v[4], g2v[4];
  int j0 = 0, j1 = 0, j2 = 0;  // nbr idx of the NEXT tile to be issued

  auto load_idx = [&](int t, int& a, int& b, int& c) {
    const int gn = t * BM + ln;
    a = nbr[3 * gn + 0];
    b = nbr[3 * gn + 1];
    c = nbr[3 * gn + 2];
  };
  auto issue_loads = [&](int t, int a, int b, int c) {
    a = a < 0 ? 0 : (a >= N_NODES ? N_NODES - 1 : a);
    b = b < 0 ? 0 : (b >= N_NODES ? N_NODES - 1 : b);
    c = c < 0 ? 0 : (c >= N_NODES ? N_NODES - 1 : c);
    const size_t gn = (size_t)t * BM + ln;
    const float4* r1 = reinterpret_cast<const float4*>(out1 + gn * 256);
    const float4* r2 = reinterpret_cast<const float4*>(out2 + gn * 256);
    const float4* g0 = reinterpret_cast<const float4*>(out2 + (size_t)a * 256);
    const float4* g1 = reinterpret_cast<const float4*>(out2 + (size_t)b * 256);
    const float4* g2 = reinterpret_cast<const float4*>(out2 + (size_t)c * 256);
#pragma unroll
    for (int r = 0; r < 4; ++r) {
      const int cc = c16 + 16 * r;
      s1[r] = r1[cc];
      s2[r] = r2[cc];
      g0v[r] = g0[cc];
      g1v[r] = g1[cc];
      g2v[r] = g2[cc];
    }
  };

  // ---- prologue: tile t0 loads + t0+1 indices ----
  {
    int a, b, c;
    load_idx(t0, a, b, c);
    issue_loads(t0, a, b, c);
    if (t0 + 1 < tEnd) load_idx(t0 + 1, j0, j1, j2);
  }

  for (int t = t0; t < tEnd; ++t) {
    // barrier 1: all waves finished reading LDS of previous tile's compute
    __builtin_amdgcn_s_barrier();

    // convert staged regs -> LDS (compiler inserts the vmcnt waits here)
#pragma unroll
    for (int r = 0; r < 4; ++r) {
      const int cc = c16 + 16 * r;
      float4 ag;
      ag.x = (s2[r].x + g0v[r].x + g1v[r].x + g2v[r].x) * 0.25f;
      ag.y = (s2[r].y + g0v[r].y + g1v[r].y + g2v[r].y) * 0.25f;
      ag.z = (s2[r].z + g0v[r].z + g1v[r].z + g2v[r].z) * 0.25f;
      ag.w = (s2[r].w + g0v[r].w + g1v[r].w + g2v[r].w) * 0.25f;
      st_bf4(&Acomb[ln * ROWC + cc * 4], s1[r]);
      st_bf4(&Acomb[ln * ROWC + 256 + cc * 4], s2[r]);
      st_bf4(&Aagg[ln * ROWA + cc * 4], ag);
    }

    // issue next tile's loads NOW; they stay in flight through compute (raw barrier
    // below does NOT drain vmcnt, unlike __syncthreads)
    if (t + 1 < tEnd) {
      issue_loads(t + 1, j0, j1, j2);
      if (t + 2 < tEnd) load_idx(t + 2, j0, j1, j2);
    }

    asm volatile("s_waitcnt lgkmcnt(0)" ::: "memory");  // my ds_writes visible
    __builtin_amdgcn_s_barrier();                        // barrier 2: LDS tile ready

    // ---- compute: wave owns cols [64w, 64w+64) of out3 AND out4 ----
    f32x4 acc3[2][4], acc4[2][4];
#pragma unroll
    for (int m = 0; m < 2; ++m)
#pragma unroll
      for (int n = 0; n < 4; ++n) {
        acc3[m][n] = (f32x4){0.f, 0.f, 0.f, 0.f};
        acc4[m][n] = (f32x4){0.f, 0.f, 0.f, 0.f};
      }

    const int nt0 = wave * 4;
    {
      const unsigned short* pc = Pc + (size_t)nt0 * 16 * 512 + lane * 8;
      const unsigned short* a_base = &Acomb[(size_t)l15 * ROWC + l4 * 8];
#pragma unroll
      for (int kt = 0; kt < 16; ++kt) {
        bf16x8 a0 = *reinterpret_cast<const bf16x8*>(a_base + kt * 32);
        bf16x8 a1 = *reinterpret_cast<const bf16x8*>(a_base + 16 * ROWC + kt * 32);
#pragma unroll
        for (int n = 0; n < 4; ++n) {
          bf16x8 b = *reinterpret_cast<const bf16x8*>(pc + ((size_t)n * 16 + kt) * 512);
          acc3[0][n] = __builtin_amdgcn_mfma_f32_16x16x32_bf16(a0, b, acc3[0][n], 0, 0, 0);
          acc3[1][n] = __builtin_amdgcn_mfma_f32_16x16x32_bf16(a1, b, acc3[1][n], 0, 0, 0);
        }
      }
    }
    {
      const unsigned short* pa = Pa + (size_t)nt0 * 8 * 512 + lane * 8;
      const unsigned short* a_base = &Aagg[(size_t)l15 * ROWA + l4 * 8];
#pragma unroll
      for (int kt = 0; kt < 8; ++kt) {
        bf16x8 a0 = *reinterpret_cast<const bf16x8*>(a_base + kt * 32);
        bf16x8 a1 = *reinterpret_cast<const bf16x8*>(a_base + 16 * ROWA + kt * 32);
#pragma unroll
        for (int n = 0; n < 4; ++n) {
          bf16x8 b = *reinterpret_cast<const bf16x8*>(pa + ((size_t)n * 8 + kt) * 512);
          acc4[0][n] = __builtin_amdgcn_mfma_f32_16x16x32_bf16(a0, b, acc4[0][n], 0, 0, 0);
          acc4[1][n] = __builtin_amdgcn_mfma_f32_16x16x32_bf16(a1, b, acc4[1][n], 0, 0, 0);
        }
      }
    }

    // ---- epilogue: D[row=(l>>4)*4+r][col=l&15] per 16x16 tile ----
    const long long node0 = (long long)t * BM;
    float* const o3base = outp + (long long)(node0)*512 + wave * 64 + l15;
    float* const o4base = o3base + (long long)N_NODES * 512;
#pragma unroll
    for (int m = 0; m < 2; ++m) {
#pragma unroll
      for (int r = 0; r < 4; ++r) {
        const long long roff = (long long)(m * 16 + l4 * 4 + r) * 512;
        float* p3 = o3base + roff;
        float* p4 = o4base + roff;
#pragma unroll
        for (int n = 0; n < 4; ++n) {
          p3[n * 16] = acc3[m][n][r] + bcv[n];
          p4[n * 16] = acc4[m][n][r] + bav[n];
        }
      }
    }
  }
}

extern "C" void kernel_launch(void* const* d_in, const int* in_sizes, int n_in,
                              void* d_out, int out_size, void* d_ws, size_t ws_size,
                              hipStream_t stream) {
  const float* out1 = (const float*)d_in[0];
  const float* out2 = (const float*)d_in[1];
  const int* nbr = (const int*)d_in[2];  // harness pushes integers as int32
  const float* Wc = (const float*)d_in[3];
  const float* bc = (const float*)d_in[4];
  const float* Wa = (const float*)d_in[5];
  const float* ba = (const float*)d_in[6];

  unsigned short* Pc = (unsigned short*)d_ws;  // 512*512 bf16 = 512 KB
  unsigned short* Pa = Pc + 512 * 512;         // 512*256 bf16 = 256 KB

  pack_w_kernel<<<192, 256, 0, stream>>>(Wc, Wa, Pc, Pa);
  const int grid = (NTILES + TPB - 1) / TPB;  // 2084
  mesh_fused_kernel<<<grid, 512, 0, stream>>>(out1, out2, nbr, Pc, Pa, bc, ba,
                                              (float*)d_out);
}

// Round 4
// 1068.111 us; speedup vs baseline: 1.0406x; 1.0406x over previous
//
#include <hip/hip_runtime.h>

// Mesh2: out3 = [out1||out2] @ W_comb^T + b_comb ; out4 = mean(self+3nbrs) @ W_agg^T + b_agg
// R2: 600us, latency-bound (31% HBM, MfmaUtil 11%, VGPR=56 -> no MLP).
// R3: T14 reg-stage pipeline, but compiler capped VGPR=128 -> spilled (~1.1GB scratch HBM
//     traffic, FETCH 545MB->1.3GB) -> 1200us.
// R4: fix register budget: __launch_bounds__(512,2) lifts VGPR cap; out3/out4 computed
//     sequentially (32 live acc VGPRs instead of 64). Pipeline structure unchanged.

typedef __bf16 bf16x8 __attribute__((ext_vector_type(8)));
typedef float f32x4 __attribute__((ext_vector_type(4)));

#define N_NODES 200000
#define BM 32
#define NTILES (N_NODES / BM)  // 6250
#define TPB 3                  // tiles per block -> grid 2084
#define ROWC 520               // 512 + 8 pad (bf16) -> 2-way-bank ds_read_b128 (free, m136)
#define ROWA 264               // 256 + 8 pad

__device__ __forceinline__ unsigned short f2bf(float x) {
  union { float f; unsigned int u; } v; v.f = x;
  return (unsigned short)((v.u + 0x7FFFu + ((v.u >> 16) & 1u)) >> 16);  // RNE
}

__device__ __forceinline__ void st_bf4(unsigned short* p, float4 f) {
  uint2 w;
  w.x = (unsigned int)f2bf(f.x) | ((unsigned int)f2bf(f.y) << 16);
  w.y = (unsigned int)f2bf(f.z) | ((unsigned int)f2bf(f.w) << 16);
  *reinterpret_cast<uint2*>(p) = w;
}

// Pack W (f32, row-major [O][K]) -> bf16 MFMA-B-fragment-linear layout:
// tile (nt,kt): lane l holds W[nt*16 + (l&15)][kt*32 + (l>>4)*8 + j], j=0..7,
// at P[tile*512 + l*8 + j].
__global__ void pack_w_kernel(const float* __restrict__ Wc,
                              const float* __restrict__ Wa,
                              unsigned short* __restrict__ Pc,
                              unsigned short* __restrict__ Pa) {
  int t = blockIdx.x * 256 + threadIdx.x;
  if (t >= (512 + 256) * 64) return;
  int lane = t & 63;
  int tile = t >> 6;
  const float* W;
  unsigned short* P;
  int K, kt_n;
  if (tile < 512) { W = Wc; P = Pc; K = 512; kt_n = 16; }
  else { tile -= 512; W = Wa; P = Pa; K = 256; kt_n = 8; }
  int nt = tile / kt_n;
  int kt = tile - nt * kt_n;
  int row = nt * 16 + (lane & 15);
  int k0 = kt * 32 + (lane >> 4) * 8;
  const float* src = W + (size_t)row * K + k0;
  unsigned short* dst = P + (size_t)tile * 512 + lane * 8;
#pragma unroll
  for (int j = 0; j < 8; ++j) dst[j] = f2bf(src[j]);
}

__global__ __launch_bounds__(512, 2) void mesh_fused_kernel(
    const float* __restrict__ out1,
    const float* __restrict__ out2,
    const int* __restrict__ nbr,
    const unsigned short* __restrict__ Pc,
    const unsigned short* __restrict__ Pa,
    const float* __restrict__ b_comb,
    const float* __restrict__ b_agg,
    float* __restrict__ outp) {
  __shared__ unsigned short Acomb[BM * ROWC];
  __shared__ unsigned short Aagg[BM * ROWA];

  const int tid = threadIdx.x;
  const int ln = tid >> 4;   // local node 0..31 (stage role)
  const int c16 = tid & 15;  // chunk lane (stage role)
  const int wave = tid >> 6, lane = tid & 63;
  const int l15 = lane & 15, l4 = lane >> 4;

  const int t0 = blockIdx.x * TPB;
  const int tEnd = (t0 + TPB < NTILES) ? t0 + TPB : NTILES;

  // bias: cols fixed per thread for the whole block -> hoist
  float bcv[4], bav[4];
#pragma unroll
  for (int n = 0; n < 4; ++n) {
    const int col = wave * 64 + n * 16 + l15;
    bcv[n] = b_comb[col];
    bav[n] = b_agg[col];
  }

  // staged registers for one tile (20 x float4 = 80 VGPR, deliberate)
  float4 s1[4], s2[4], g0v[4], g1v[4], g2v[4];
  int j0 = 0, j1 = 0, j2 = 0;  // nbr idx of the NEXT tile to be issued

  auto load_idx = [&](int t, int& a, int& b, int& c) {
    const int gn = t * BM + ln;
    a = nbr[3 * gn + 0];
    b = nbr[3 * gn + 1];
    c = nbr[3 * gn + 2];
  };
  auto issue_loads = [&](int t, int a, int b, int c) {
    a = a < 0 ? 0 : (a >= N_NODES ? N_NODES - 1 : a);
    b = b < 0 ? 0 : (b >= N_NODES ? N_NODES - 1 : b);
    c = c < 0 ? 0 : (c >= N_NODES ? N_NODES - 1 : c);
    const size_t gn = (size_t)t * BM + ln;
    const float4* r1 = reinterpret_cast<const float4*>(out1 + gn * 256);
    const float4* r2 = reinterpret_cast<const float4*>(out2 + gn * 256);
    const float4* g0 = reinterpret_cast<const float4*>(out2 + (size_t)a * 256);
    const float4* g1 = reinterpret_cast<const float4*>(out2 + (size_t)b * 256);
    const float4* g2 = reinterpret_cast<const float4*>(out2 + (size_t)c * 256);
#pragma unroll
    for (int r = 0; r < 4; ++r) {
      const int cc = c16 + 16 * r;
      s1[r] = r1[cc];
      s2[r] = r2[cc];
      g0v[r] = g0[cc];
      g1v[r] = g1[cc];
      g2v[r] = g2[cc];
    }
  };

  // ---- prologue: tile t0 loads + t0+1 indices ----
  {
    int a, b, c;
    load_idx(t0, a, b, c);
    issue_loads(t0, a, b, c);
    if (t0 + 1 < tEnd) load_idx(t0 + 1, j0, j1, j2);
  }

  for (int t = t0; t < tEnd; ++t) {
    // barrier 1: all waves finished reading LDS of previous tile's compute
    __builtin_amdgcn_s_barrier();

    // convert staged regs -> LDS (compiler inserts the vmcnt waits here)
#pragma unroll
    for (int r = 0; r < 4; ++r) {
      const int cc = c16 + 16 * r;
      float4 ag;
      ag.x = (s2[r].x + g0v[r].x + g1v[r].x + g2v[r].x) * 0.25f;
      ag.y = (s2[r].y + g0v[r].y + g1v[r].y + g2v[r].y) * 0.25f;
      ag.z = (s2[r].z + g0v[r].z + g1v[r].z + g2v[r].z) * 0.25f;
      ag.w = (s2[r].w + g0v[r].w + g1v[r].w + g2v[r].w) * 0.25f;
      st_bf4(&Acomb[ln * ROWC + cc * 4], s1[r]);
      st_bf4(&Acomb[ln * ROWC + 256 + cc * 4], s2[r]);
      st_bf4(&Aagg[ln * ROWA + cc * 4], ag);
    }

    // issue next tile's loads NOW; they stay in flight through compute (raw barrier
    // below does NOT drain vmcnt, unlike __syncthreads)
    if (t + 1 < tEnd) {
      issue_loads(t + 1, j0, j1, j2);
      if (t + 2 < tEnd) load_idx(t + 2, j0, j1, j2);
    }

    asm volatile("s_waitcnt lgkmcnt(0)" ::: "memory");  // my ds_writes visible
    __builtin_amdgcn_s_barrier();                        // barrier 2: LDS tile ready

    const int nt0 = wave * 4;
    const long long node0 = (long long)t * BM;
    float* const o3base = outp + node0 * 512 + wave * 64 + l15;
    float* const o4base = o3base + (long long)N_NODES * 512;

    // ---- out3 first (acc live range limited to this scope: 32 VGPRs) ----
    {
      f32x4 acc3[2][4];
#pragma unroll
      for (int m = 0; m < 2; ++m)
#pragma unroll
        for (int n = 0; n < 4; ++n) acc3[m][n] = (f32x4){0.f, 0.f, 0.f, 0.f};

      const unsigned short* pc = Pc + (size_t)nt0 * 16 * 512 + lane * 8;
      const unsigned short* a_base = &Acomb[(size_t)l15 * ROWC + l4 * 8];
#pragma unroll
      for (int kt = 0; kt < 16; ++kt) {
        bf16x8 a0 = *reinterpret_cast<const bf16x8*>(a_base + kt * 32);
        bf16x8 a1 = *reinterpret_cast<const bf16x8*>(a_base + 16 * ROWC + kt * 32);
#pragma unroll
        for (int n = 0; n < 4; ++n) {
          bf16x8 b = *reinterpret_cast<const bf16x8*>(pc + ((size_t)n * 16 + kt) * 512);
          acc3[0][n] = __builtin_amdgcn_mfma_f32_16x16x32_bf16(a0, b, acc3[0][n], 0, 0, 0);
          acc3[1][n] = __builtin_amdgcn_mfma_f32_16x16x32_bf16(a1, b, acc3[1][n], 0, 0, 0);
        }
      }
#pragma unroll
      for (int m = 0; m < 2; ++m)
#pragma unroll
        for (int r = 0; r < 4; ++r) {
          float* p3 = o3base + (long long)(m * 16 + l4 * 4 + r) * 512;
#pragma unroll
          for (int n = 0; n < 4; ++n) p3[n * 16] = acc3[m][n][r] + bcv[n];
        }
    }

    // ---- out4 second ----
    {
      f32x4 acc4[2][4];
#pragma unroll
      for (int m = 0; m < 2; ++m)
#pragma unroll
        for (int n = 0; n < 4; ++n) acc4[m][n] = (f32x4){0.f, 0.f, 0.f, 0.f};

      const unsigned short* pa = Pa + (size_t)nt0 * 8 * 512 + lane * 8;
      const unsigned short* a_base = &Aagg[(size_t)l15 * ROWA + l4 * 8];
#pragma unroll
      for (int kt = 0; kt < 8; ++kt) {
        bf16x8 a0 = *reinterpret_cast<const bf16x8*>(a_base + kt * 32);
        bf16x8 a1 = *reinterpret_cast<const bf16x8*>(a_base + 16 * ROWA + kt * 32);
#pragma unroll
        for (int n = 0; n < 4; ++n) {
          bf16x8 b = *reinterpret_cast<const bf16x8*>(pa + ((size_t)n * 8 + kt) * 512);
          acc4[0][n] = __builtin_amdgcn_mfma_f32_16x16x32_bf16(a0, b, acc4[0][n], 0, 0, 0);
          acc4[1][n] = __builtin_amdgcn_mfma_f32_16x16x32_bf16(a1, b, acc4[1][n], 0, 0, 0);
        }
      }
#pragma unroll
      for (int m = 0; m < 2; ++m)
#pragma unroll
        for (int r = 0; r < 4; ++r) {
          float* p4 = o4base + (long long)(m * 16 + l4 * 4 + r) * 512;
#pragma unroll
          for (int n = 0; n < 4; ++n) p4[n * 16] = acc4[m][n][r] + bav[n];
        }
    }
  }
}

extern "C" void kernel_launch(void* const* d_in, const int* in_sizes, int n_in,
                              void* d_out, int out_size, void* d_ws, size_t ws_size,
                              hipStream_t stream) {
  const float* out1 = (const float*)d_in[0];
  const float* out2 = (const float*)d_in[1];
  const int* nbr = (const int*)d_in[2];  // harness pushes integers as int32
  const float* Wc = (const float*)d_in[3];
  const float* bc = (const float*)d_in[4];
  const float* Wa = (const float*)d_in[5];
  const float* ba = (const float*)d_in[6];

  unsigned short* Pc = (unsigned short*)d_ws;  // 512*512 bf16 = 512 KB
  unsigned short* Pa = Pc + 512 * 512;         // 512*256 bf16 = 256 KB

  pack_w_kernel<<<192, 256, 0, stream>>>(Wc, Wa, Pc, Pa);
  const int grid = (NTILES + TPB - 1) / TPB;  // 2084
  mesh_fused_kernel<<<grid, 512, 0, stream>>>(out1, out2, nbr, Pc, Pa, bc, ba,
                                              (float*)d_out);
}